// Round 1
// baseline (237.518 us; speedup 1.0000x reference)
//
#include <hip/hip_runtime.h>

// LIF scan: per spatial site i, for t in 0..7:
//   mem   = mem * DECAY * (1 - spike) + x[t*N + i]
//   spike = (mem >= THRESH) ? 1 : 0   -> out[t*N + i]
// Memory-bound elementwise-with-recurrence: one thread per float4 (4 sites),
// t-loop fully unrolled in registers. 268 MB total traffic -> ~43 us floor.

#define DECAY  0.25f
#define THRESH 0.5f

__global__ __launch_bounds__(256) void lif_scan_kernel(
    const float4* __restrict__ x, float4* __restrict__ out, int n4) {
    const int i = blockIdx.x * blockDim.x + threadIdx.x;
    if (i >= n4) return;

    float4 mem   = make_float4(0.f, 0.f, 0.f, 0.f);
    float4 spike = make_float4(0.f, 0.f, 0.f, 0.f);

#pragma unroll
    for (int t = 0; t < 8; ++t) {
        const float4 xv = x[(size_t)t * (size_t)n4 + (size_t)i];
        mem.x = mem.x * (DECAY * (1.f - spike.x)) + xv.x;
        mem.y = mem.y * (DECAY * (1.f - spike.y)) + xv.y;
        mem.z = mem.z * (DECAY * (1.f - spike.z)) + xv.z;
        mem.w = mem.w * (DECAY * (1.f - spike.w)) + xv.w;
        spike.x = (mem.x >= THRESH) ? 1.f : 0.f;
        spike.y = (mem.y >= THRESH) ? 1.f : 0.f;
        spike.z = (mem.z >= THRESH) ? 1.f : 0.f;
        spike.w = (mem.w >= THRESH) ? 1.f : 0.f;
        out[(size_t)t * (size_t)n4 + (size_t)i] = spike;
    }
}

extern "C" void kernel_launch(void* const* d_in, const int* in_sizes, int n_in,
                              void* d_out, int out_size, void* d_ws, size_t ws_size,
                              hipStream_t stream) {
    const float* x = (const float*)d_in[0];
    float* out = (float*)d_out;

    const int total = in_sizes[0];        // 8 * 32 * 128 * 32 * 32 = 33,554,432
    const int T = 8;
    const int n = total / T;              // 4,194,304 sites per timestep
    const int n4 = n / 4;                 // 1,048,576 float4 groups (n divisible by 4)

    const int block = 256;
    const int grid = (n4 + block - 1) / block;  // 4096 blocks

    lif_scan_kernel<<<grid, block, 0, stream>>>(
        (const float4*)x, (float4*)out, n4);
}